// Round 3
// baseline (628.353 us; speedup 1.0000x reference)
//
#include <hip/hip_runtime.h>
#include <hip/hip_fp16.h>

#define CCH 48        // channels
#define NPB 128       // nodes per bucket (1<<7); requires N <= 128*1024
#define NPB_SH 7
#define MAXNB 1024    // max buckets the LDS histograms support
#define SCAT_EPB 4096 // edges per scatter block (256 thr x 16)

// --- k1: block-aggregated scatter into fixed-capacity bucket regions ---
// col side: packed record  row | (col&127)<<24  (4B)  -> pairs[b*CAP + ...]
// row side: 1-byte record  row&127                    -> rbytes[b*CAP + ...]
__global__ void __launch_bounds__(256) bucket_scatter(const int* __restrict__ row,
                                                      const int* __restrict__ col,
                                                      int* __restrict__ colCur,
                                                      int* __restrict__ rowCur,
                                                      int* __restrict__ pairs,
                                                      unsigned char* __restrict__ rbytes,
                                                      int NB, int E, int CAP) {
    __shared__ int sc[MAXNB], sr[MAXNB];
    int tid = threadIdx.x;
    for (int i = tid; i < NB; i += 256) { sc[i] = 0; sr[i] = 0; }
    __syncthreads();
    int base = blockIdx.x * SCAT_EPB;
    int r[16], c[16];
    bool full = (base + SCAT_EPB <= E);
    if (full) {
#pragma unroll
        for (int k = 0; k < 4; ++k) {
            int idx = base + (k * 256 + tid) * 4;
            *reinterpret_cast<int4*>(&c[k * 4]) = *reinterpret_cast<const int4*>(col + idx);
            *reinterpret_cast<int4*>(&r[k * 4]) = *reinterpret_cast<const int4*>(row + idx);
        }
#pragma unroll
        for (int k = 0; k < 16; ++k) {
            atomicAdd(&sc[c[k] >> NPB_SH], 1);
            atomicAdd(&sr[r[k] >> NPB_SH], 1);
        }
    } else {
#pragma unroll
        for (int k = 0; k < 16; ++k) {
            int e = base + k * 256 + tid;
            if (e < E) {
                c[k] = col[e]; r[k] = row[e];
                atomicAdd(&sc[c[k] >> NPB_SH], 1);
                atomicAdd(&sr[r[k] >> NPB_SH], 1);
            } else {
                c[k] = -1;
            }
        }
    }
    __syncthreads();
    // reserve ranges: one global atomic per (block,bucket); LDS slot -> absolute cursor
    for (int i = tid; i < NB; i += 256) {
        int nc = sc[i];
        if (nc) sc[i] = i * CAP + atomicAdd(colCur + i, nc);
        int nr = sr[i];
        if (nr) sr[i] = i * CAP + atomicAdd(rowCur + i, nr);
    }
    __syncthreads();
    if (full) {
#pragma unroll
        for (int k = 0; k < 16; ++k) {
            int cc = c[k], rr = r[k];
            int p = atomicAdd(&sc[cc >> NPB_SH], 1);
            pairs[p] = rr | ((cc & (NPB - 1)) << 24);
            int q = atomicAdd(&sr[rr >> NPB_SH], 1);
            rbytes[q] = (unsigned char)(rr & (NPB - 1));
        }
    } else {
#pragma unroll
        for (int k = 0; k < 16; ++k) {
            if (c[k] >= 0) {
                int cc = c[k], rr = r[k];
                int p = atomicAdd(&sc[cc >> NPB_SH], 1);
                pairs[p] = rr | ((cc & (NPB - 1)) << 24);
                int q = atomicAdd(&sr[rr >> NPB_SH], 1);
                rbytes[q] = (unsigned char)(rr & (NPB - 1));
            }
        }
    }
}

// --- k2: per-bucket row-degree histogram -> dis, fused fp16 scale-convert ---
// lab16[n,c] = (half)(dis[n] * label[n,c])
__global__ void __launch_bounds__(256) deg_convert(const unsigned char* __restrict__ rbytes,
                                                   const int* __restrict__ rowCur,
                                                   const float* __restrict__ label,
                                                   float* __restrict__ dis,
                                                   __half* __restrict__ lab16,
                                                   int N, int CAP) {
    __shared__ int cnt[NPB];
    __shared__ float ds[NPB];
    int b = blockIdx.x, tid = threadIdx.x;
    if (tid < NPB) cnt[tid] = 0;
    __syncthreads();
    int beg = b * CAP, rnum = rowCur[b];
    int nq = rnum >> 2;
    for (int q = tid; q < nq; q += 256) {
        uchar4 u = *reinterpret_cast<const uchar4*>(rbytes + beg + q * 4);
        atomicAdd(&cnt[u.x], 1);
        atomicAdd(&cnt[u.y], 1);
        atomicAdd(&cnt[u.z], 1);
        atomicAdd(&cnt[u.w], 1);
    }
    for (int i = (nq << 2) + tid; i < rnum; i += 256)
        atomicAdd(&cnt[rbytes[beg + i]], 1);
    __syncthreads();
    int n0 = b << NPB_SH;
    if (tid < NPB) {
        float w = rsqrtf((float)cnt[tid] + 1.0f);
        ds[tid] = w;
        if (n0 + tid < N) dis[n0 + tid] = w;
    }
    __syncthreads();
    int r = tid >> 1, hf = tid & 1;
    int n = n0 + r;
    if (n < N) {
        float w = ds[r];
        const float4* src = reinterpret_cast<const float4*>(label + (size_t)n * CCH + hf * 24);
        uint4* dst = reinterpret_cast<uint4*>(lab16 + (size_t)n * CCH + hf * 24);
#pragma unroll
        for (int k = 0; k < 3; ++k) {
            float4 a = src[2 * k];
            float4 c = src[2 * k + 1];
            union { __half2 h[4]; uint4 u; } pk;
            pk.h[0] = __floats2half2_rn(w * a.x, w * a.y);
            pk.h[1] = __floats2half2_rn(w * a.z, w * a.w);
            pk.h[2] = __floats2half2_rn(w * c.x, w * c.y);
            pk.h[3] = __floats2half2_rn(w * c.z, w * c.w);
            dst[k] = pk.u;
        }
    }
}

// --- k3: push-gather, one block per col-bucket, LDS accumulator tile ---
// acc[c][ch] += lab16[src][ch] for every pair in the bucket, then
// out[n][ch] = dis[n] * (acc + lab16[n][ch])
__global__ void __launch_bounds__(256) gather_push(const int* __restrict__ pairs,
                                                   const int* __restrict__ colCur,
                                                   const __half* __restrict__ lab16,
                                                   const float* __restrict__ dis,
                                                   float* __restrict__ out,
                                                   int N, int CAP) {
    __shared__ float acc[NPB * CCH];  // 24 KiB
    int b = blockIdx.x, tid = threadIdx.x;
    for (int i = tid; i < NPB * CCH; i += 256) acc[i] = 0.f;
    __syncthreads();
    int beg = b * CAP;
    int cnum = colCur[b];
    int gid = tid >> 3;
    int lane6 = (tid & 7) * 6;
    int i = gid;
    for (; i + 32 < cnum; i += 64) {
        int pk0 = pairs[beg + i];
        int pk1 = pairs[beg + i + 32];
        int s0 = pk0 & 0x00FFFFFF;
        int c0 = ((unsigned)pk0) >> 24;
        int s1 = pk1 & 0x00FFFFFF;
        int c1 = ((unsigned)pk1) >> 24;
        const __half2* p0 = reinterpret_cast<const __half2*>(lab16 + (size_t)s0 * CCH + lane6);
        const __half2* p1 = reinterpret_cast<const __half2*>(lab16 + (size_t)s1 * CCH + lane6);
        __half2 x0 = p0[0], x1 = p0[1], x2 = p0[2];
        __half2 y0 = p1[0], y1 = p1[1], y2 = p1[2];
        float* a0 = acc + c0 * CCH + lane6;
        float* a1 = acc + c1 * CCH + lane6;
        float2 f;
        f = __half22float2(x0); atomicAdd(a0 + 0, f.x); atomicAdd(a0 + 1, f.y);
        f = __half22float2(x1); atomicAdd(a0 + 2, f.x); atomicAdd(a0 + 3, f.y);
        f = __half22float2(x2); atomicAdd(a0 + 4, f.x); atomicAdd(a0 + 5, f.y);
        f = __half22float2(y0); atomicAdd(a1 + 0, f.x); atomicAdd(a1 + 1, f.y);
        f = __half22float2(y1); atomicAdd(a1 + 2, f.x); atomicAdd(a1 + 3, f.y);
        f = __half22float2(y2); atomicAdd(a1 + 4, f.x); atomicAdd(a1 + 5, f.y);
    }
    if (i < cnum) {
        int pk0 = pairs[beg + i];
        int s0 = pk0 & 0x00FFFFFF;
        int c0 = ((unsigned)pk0) >> 24;
        const __half2* p0 = reinterpret_cast<const __half2*>(lab16 + (size_t)s0 * CCH + lane6);
        __half2 x0 = p0[0], x1 = p0[1], x2 = p0[2];
        float* a0 = acc + c0 * CCH + lane6;
        float2 f;
        f = __half22float2(x0); atomicAdd(a0 + 0, f.x); atomicAdd(a0 + 1, f.y);
        f = __half22float2(x1); atomicAdd(a0 + 2, f.x); atomicAdd(a0 + 3, f.y);
        f = __half22float2(x2); atomicAdd(a0 + 4, f.x); atomicAdd(a0 + 5, f.y);
    }
    __syncthreads();
    // output: 2 threads per node, 24 channels each; self term from lab16 row
    int r = tid >> 1, hf = tid & 1;
    int n = (b << NPB_SH) + r;
    if (n < N) {
        float dn = dis[n];
        const __half2* ps = reinterpret_cast<const __half2*>(lab16 + (size_t)n * CCH + hf * 24);
        const float* a = acc + r * CCH + hf * 24;
        float4* o = reinterpret_cast<float4*>(out + (size_t)n * CCH + hf * 24);
#pragma unroll
        for (int k = 0; k < 6; ++k) {
            float2 f = __half22float2(ps[2 * k]);
            float2 g = __half22float2(ps[2 * k + 1]);
            float4 v;
            v.x = dn * (a[4 * k + 0] + f.x);
            v.y = dn * (a[4 * k + 1] + f.y);
            v.z = dn * (a[4 * k + 2] + g.x);
            v.w = dn * (a[4 * k + 3] + g.y);
            o[k] = v;
        }
    }
}

extern "C" void kernel_launch(void* const* d_in, const int* in_sizes, int n_in,
                              void* d_out, int out_size, void* d_ws, size_t ws_size,
                              hipStream_t stream) {
    const float* label = (const float*)d_in[0];  // fp32 (N,48)
    const int* ei = (const int*)d_in[1];         // int32, (2,E) flat

    const int NC = in_sizes[0];  // N * 48
    const int N  = NC / CCH;
    const int E  = in_sizes[1] / 2;
    const int* row = ei;
    const int* col = ei + E;

    const int NB = (N + NPB - 1) / NPB;  // 782 buckets at N=100000
    const int avg = (E + NB - 1) / NB;   // ~2047
    int slack = avg / 4; if (slack < 768) slack = 768;
    const int CAP = (avg + slack + 15) & ~15;  // ~17 sigma slack

    // ws layout (16B-aligned sections):
    // [pairs NB*CAP int] [colCur NB][rowCur NB] [dis N f32] [pad]
    // [rbytes NB*CAP bytes] [lab16 N*48 half]
    int* pairs = (int*)d_ws;
    int* colCur = pairs + (size_t)NB * CAP;
    int* rowCur = colCur + NB;
    float* dis = (float*)(rowCur + NB);
    size_t rb_off = (((size_t)(dis + N) - (size_t)d_ws) + 15) & ~(size_t)15;
    unsigned char* rbytes = (unsigned char*)d_ws + rb_off;
    __half* lab16 = (__half*)(rbytes + (size_t)NB * CAP);

    // zero the two cursor arrays (~6 KB)
    hipMemsetAsync(colCur, 0, (size_t)(2 * NB) * sizeof(int), stream);

    int sblocks = (E + SCAT_EPB - 1) / SCAT_EPB;
    bucket_scatter<<<sblocks, 256, 0, stream>>>(row, col, colCur, rowCur,
                                                pairs, rbytes, NB, E, CAP);
    deg_convert<<<NB, 256, 0, stream>>>(rbytes, rowCur, label, dis, lab16, N, CAP);
    gather_push<<<NB, 256, 0, stream>>>(pairs, colCur, lab16, dis,
                                        (float*)d_out, N, CAP);
}

// Round 4
// 164.118 us; speedup vs baseline: 3.8287x; 3.8287x over previous
//
#include <hip/hip_runtime.h>
#include <hip/hip_fp16.h>

#define CCH 48        // channels
#define NPB 128       // nodes per bucket (1<<7); requires N <= 128*1024
#define NPB_SH 7
#define MAXNB 1024    // max buckets the LDS histograms support
#define SCAT_EPB 8192 // edges per scatter block (256 thr x 32)

// --- k1: block-aggregated scatter into fixed-capacity bucket regions ---
// col side: packed record  row | (col&127)<<24  (4B) -> pairs[b*CAP...], reservations
//           rounded up to 16 ints (full 64B lines), pad filled with -1 sentinels.
// row side: 1-byte record  row&127 -> rbytes[b*CAP...], unpadded (exact counts).
__global__ void __launch_bounds__(256) bucket_scatter(const int* __restrict__ row,
                                                      const int* __restrict__ col,
                                                      int* __restrict__ colCur,
                                                      int* __restrict__ rowCur,
                                                      int* __restrict__ pairs,
                                                      unsigned char* __restrict__ rbytes,
                                                      int NB, int E, int CAP) {
    __shared__ int sc[MAXNB], sr[MAXNB];
    int tid = threadIdx.x;
    for (int i = tid; i < NB; i += 256) { sc[i] = 0; sr[i] = 0; }
    __syncthreads();
    int base = blockIdx.x * SCAT_EPB;
    int r[32], c[32];
    bool full = (base + SCAT_EPB <= E);
    if (full) {
#pragma unroll
        for (int k = 0; k < 8; ++k) {
            int idx = base + (k * 256 + tid) * 4;
            *reinterpret_cast<int4*>(&c[k * 4]) = *reinterpret_cast<const int4*>(col + idx);
            *reinterpret_cast<int4*>(&r[k * 4]) = *reinterpret_cast<const int4*>(row + idx);
        }
#pragma unroll
        for (int k = 0; k < 32; ++k) {
            atomicAdd(&sc[c[k] >> NPB_SH], 1);
            atomicAdd(&sr[r[k] >> NPB_SH], 1);
        }
    } else {
#pragma unroll
        for (int k = 0; k < 32; ++k) {
            int e = base + k * 256 + tid;
            if (e < E) {
                c[k] = col[e]; r[k] = row[e];
                atomicAdd(&sc[c[k] >> NPB_SH], 1);
                atomicAdd(&sr[r[k] >> NPB_SH], 1);
            } else {
                c[k] = -1;
            }
        }
    }
    __syncthreads();
    // reserve ranges: one global atomic per (block,bucket); LDS slot -> absolute base
    for (int i = tid; i < NB; i += 256) {
        int nc = sc[i];
        if (nc) {
            int padded = (nc + 15) & ~15;               // line-aligned reservation
            int b0 = i * CAP + atomicAdd(colCur + i, padded);
            sc[i] = b0;
            for (int j = nc; j < padded; ++j) pairs[b0 + j] = -1;  // pads share block's lines
        }
        int nr = sr[i];
        if (nr) sr[i] = i * CAP + atomicAdd(rowCur + i, nr);
    }
    __syncthreads();
    if (full) {
#pragma unroll
        for (int k = 0; k < 32; ++k) {
            int cc = c[k], rr = r[k];
            int p = atomicAdd(&sc[cc >> NPB_SH], 1);
            pairs[p] = rr | ((cc & (NPB - 1)) << 24);
            int q = atomicAdd(&sr[rr >> NPB_SH], 1);
            rbytes[q] = (unsigned char)(rr & (NPB - 1));
        }
    } else {
#pragma unroll
        for (int k = 0; k < 32; ++k) {
            if (c[k] >= 0) {
                int cc = c[k], rr = r[k];
                int p = atomicAdd(&sc[cc >> NPB_SH], 1);
                pairs[p] = rr | ((cc & (NPB - 1)) << 24);
                int q = atomicAdd(&sr[rr >> NPB_SH], 1);
                rbytes[q] = (unsigned char)(rr & (NPB - 1));
            }
        }
    }
}

// --- k2: per-bucket CSR build (in-place via LDS stage, sentinel-skip) +
//         row-degree -> dis + fused fp16 scale-convert of the bucket's rows ---
__global__ void __launch_bounds__(256) csr_deg_conv(int* __restrict__ pairs,
                                                    const int* __restrict__ colCur,
                                                    const unsigned char* __restrict__ rbytes,
                                                    const int* __restrict__ rowCur,
                                                    const float* __restrict__ label,
                                                    int2* __restrict__ ptr2,
                                                    float* __restrict__ dis,
                                                    __half* __restrict__ lab16,
                                                    int N, int CAP) {
    extern __shared__ int stage[];  // CAP ints
    __shared__ int cnt[NPB], scn[NPB];
    __shared__ float ds[NPB];
    int b = blockIdx.x, tid = threadIdx.x;
    int beg = b * CAP;
    int cnum = colCur[b];  // padded count (multiple of 16)
    if (tid < NPB) cnt[tid] = 0;
    __syncthreads();
    int nq = cnum >> 2;
    for (int q = tid; q < nq; q += 256) {
        int4 pk = *reinterpret_cast<const int4*>(pairs + beg + q * 4);
        *reinterpret_cast<int4*>(stage + q * 4) = pk;
        if (pk.x >= 0) atomicAdd(&cnt[((unsigned)pk.x) >> 24], 1);
        if (pk.y >= 0) atomicAdd(&cnt[((unsigned)pk.y) >> 24], 1);
        if (pk.z >= 0) atomicAdd(&cnt[((unsigned)pk.z) >> 24], 1);
        if (pk.w >= 0) atomicAdd(&cnt[((unsigned)pk.w) >> 24], 1);
    }
    __syncthreads();
    int v = (tid < NPB) ? cnt[tid] : 0;
    if (tid < NPB) scn[tid] = v;
    __syncthreads();
    for (int off = 1; off < NPB; off <<= 1) {
        int t = (tid >= off && tid < NPB) ? scn[tid - off] : 0;
        __syncthreads();
        if (tid < NPB) scn[tid] += t;
        __syncthreads();
    }
    int n0 = b << NPB_SH;
    if (tid < NPB) {
        int start = beg + scn[tid] - v;  // exclusive prefix, absolute
        int n = n0 + tid;
        if (n < N) ptr2[n] = make_int2(start, start + v);
        cnt[tid] = start;  // absolute cursor
    }
    __syncthreads();
    // scatter src ids back over the same region (stage holds originals)
    for (int i = tid; i < cnum; i += 256) {
        int pk = stage[i];
        if (pk >= 0) {
            int p = atomicAdd(&cnt[((unsigned)pk) >> 24], 1);
            pairs[p] = pk & 0x00FFFFFF;
        }
    }
    // --- row side: degree histogram -> dis ---
    __syncthreads();
    if (tid < NPB) cnt[tid] = 0;
    __syncthreads();
    int rnum = rowCur[b];
    int nq4 = rnum >> 2;
    for (int q = tid; q < nq4; q += 256) {
        uchar4 u = *reinterpret_cast<const uchar4*>(rbytes + beg + q * 4);
        atomicAdd(&cnt[u.x], 1);
        atomicAdd(&cnt[u.y], 1);
        atomicAdd(&cnt[u.z], 1);
        atomicAdd(&cnt[u.w], 1);
    }
    for (int i = (nq4 << 2) + tid; i < rnum; i += 256)
        atomicAdd(&cnt[rbytes[beg + i]], 1);
    __syncthreads();
    if (tid < NPB) {
        float w = rsqrtf((float)cnt[tid] + 1.0f);
        ds[tid] = w;
        if (n0 + tid < N) dis[n0 + tid] = w;
    }
    __syncthreads();
    // --- fused convert: lab16[n,c] = (half)(dis[n]*label[n,c]), 2 thr/row ---
    int rr = tid >> 1, hf = tid & 1;
    int n = n0 + rr;
    if (n < N) {
        float w = ds[rr];
        const float4* src4 = reinterpret_cast<const float4*>(label + (size_t)n * CCH + hf * 24);
        uint4* dst = reinterpret_cast<uint4*>(lab16 + (size_t)n * CCH + hf * 24);
#pragma unroll
        for (int k = 0; k < 3; ++k) {
            float4 a = src4[2 * k];
            float4 cc = src4[2 * k + 1];
            union { __half2 h[4]; uint4 u; } pkk;
            pkk.h[0] = __floats2half2_rn(w * a.x, w * a.y);
            pkk.h[1] = __floats2half2_rn(w * a.z, w * a.w);
            pkk.h[2] = __floats2half2_rn(w * cc.x, w * cc.y);
            pkk.h[3] = __floats2half2_rn(w * cc.z, w * cc.w);
            dst[k] = pkk.u;
        }
    }
}

// --- k3: pull-gather over fp16 pre-scaled rows; 8 lanes/node, 6 ch/lane, 4-edge unroll ---
// out[n,c] = dis[n] * ( sum_{e: col=n} lab16[src,c] + lab16[n,c] )
__global__ void __launch_bounds__(256) gather16(const __half* __restrict__ lab16,
                                                const int2* __restrict__ ptr2,
                                                const int* __restrict__ srcA,
                                                const float* __restrict__ dis,
                                                float* __restrict__ out, int N) {
    int t = blockIdx.x * blockDim.x + threadIdx.x;
    int n = t >> 3;
    if (n >= N) return;
    int c0 = (t & 7) * 6;
    int2 be = ptr2[n];
    float a0 = 0.f, a1 = 0.f, a2 = 0.f, a3 = 0.f, a4 = 0.f, a5 = 0.f;
    int i = be.x, end = be.y;
    for (; i + 4 <= end; i += 4) {
        int s0 = srcA[i], s1 = srcA[i + 1], s2 = srcA[i + 2], s3 = srcA[i + 3];
        const __half2* p0 = reinterpret_cast<const __half2*>(lab16 + (size_t)s0 * CCH + c0);
        const __half2* p1 = reinterpret_cast<const __half2*>(lab16 + (size_t)s1 * CCH + c0);
        const __half2* p2 = reinterpret_cast<const __half2*>(lab16 + (size_t)s2 * CCH + c0);
        const __half2* p3 = reinterpret_cast<const __half2*>(lab16 + (size_t)s3 * CCH + c0);
        __half2 x0 = p0[0], x1 = p0[1], x2 = p0[2];
        __half2 y0 = p1[0], y1 = p1[1], y2 = p1[2];
        __half2 z0 = p2[0], z1 = p2[1], z2 = p2[2];
        __half2 w0 = p3[0], w1 = p3[1], w2 = p3[2];
        float2 f;
        f = __half22float2(x0); a0 += f.x; a1 += f.y;
        f = __half22float2(x1); a2 += f.x; a3 += f.y;
        f = __half22float2(x2); a4 += f.x; a5 += f.y;
        f = __half22float2(y0); a0 += f.x; a1 += f.y;
        f = __half22float2(y1); a2 += f.x; a3 += f.y;
        f = __half22float2(y2); a4 += f.x; a5 += f.y;
        f = __half22float2(z0); a0 += f.x; a1 += f.y;
        f = __half22float2(z1); a2 += f.x; a3 += f.y;
        f = __half22float2(z2); a4 += f.x; a5 += f.y;
        f = __half22float2(w0); a0 += f.x; a1 += f.y;
        f = __half22float2(w1); a2 += f.x; a3 += f.y;
        f = __half22float2(w2); a4 += f.x; a5 += f.y;
    }
    for (; i < end; ++i) {
        int s0 = srcA[i];
        const __half2* p0 = reinterpret_cast<const __half2*>(lab16 + (size_t)s0 * CCH + c0);
        __half2 x0 = p0[0], x1 = p0[1], x2 = p0[2];
        float2 f;
        f = __half22float2(x0); a0 += f.x; a1 += f.y;
        f = __half22float2(x1); a2 += f.x; a3 += f.y;
        f = __half22float2(x2); a4 += f.x; a5 += f.y;
    }
    // self loop: lab16[n] is already dis[n]*label[n]
    {
        const __half2* ps = reinterpret_cast<const __half2*>(lab16 + (size_t)n * CCH + c0);
        __half2 x0 = ps[0], x1 = ps[1], x2 = ps[2];
        float2 f;
        f = __half22float2(x0); a0 += f.x; a1 += f.y;
        f = __half22float2(x1); a2 += f.x; a3 += f.y;
        f = __half22float2(x2); a4 += f.x; a5 += f.y;
    }
    float dn = dis[n];
    float* o = out + (size_t)n * CCH + c0;
    o[0] = dn * a0; o[1] = dn * a1; o[2] = dn * a2;
    o[3] = dn * a3; o[4] = dn * a4; o[5] = dn * a5;
}

extern "C" void kernel_launch(void* const* d_in, const int* in_sizes, int n_in,
                              void* d_out, int out_size, void* d_ws, size_t ws_size,
                              hipStream_t stream) {
    const float* label = (const float*)d_in[0];  // fp32 (N,48)
    const int* ei = (const int*)d_in[1];         // int32, (2,E) flat

    const int NC = in_sizes[0];  // N * 48
    const int N  = NC / CCH;
    const int E  = in_sizes[1] / 2;
    const int* row = ei;
    const int* col = ei + E;

    const int NB = (N + NPB - 1) >> NPB_SH;             // 782 at N=100000
    const int sblocks = (E + SCAT_EPB - 1) / SCAT_EPB;  // 196 at E=1.6M
    const int avg = (E + NB - 1) / NB;                  // ~2047
    // padded bucket total <= actual + 15*sblocks; plus ~11-sigma slack
    const int CAP = (avg + 15 * sblocks + 512 + 15) & ~15;  // ~5504

    // ws layout (16B-aligned sections):
    // [pairs NB*CAP int] [colCur NB][rowCur NB] [ptr2 N int2] [dis N f32] [pad]
    // [rbytes NB*CAP bytes] [lab16 N*48 half]
    int* pairs = (int*)d_ws;
    int* colCur = pairs + (size_t)NB * CAP;
    int* rowCur = colCur + NB;
    int2* ptr2 = (int2*)(rowCur + NB);
    float* dis = (float*)(ptr2 + N);
    size_t rb_off = (((size_t)(dis + N) - (size_t)d_ws) + 15) & ~(size_t)15;
    unsigned char* rbytes = (unsigned char*)d_ws + rb_off;
    __half* lab16 = (__half*)(rbytes + (size_t)NB * CAP);

    // zero the two cursor arrays (~6 KB)
    hipMemsetAsync(colCur, 0, (size_t)(2 * NB) * sizeof(int), stream);

    bucket_scatter<<<sblocks, 256, 0, stream>>>(row, col, colCur, rowCur,
                                                pairs, rbytes, NB, E, CAP);
    csr_deg_conv<<<NB, 256, (size_t)CAP * sizeof(int), stream>>>(
        pairs, colCur, rbytes, rowCur, label, ptr2, dis, lab16, N, CAP);
    gather16<<<(N * 8 + 255) / 256, 256, 0, stream>>>(lab16, ptr2, pairs /*srcA in-place*/,
                                                      dis, (float*)d_out, N);
}